// Round 7
// baseline (49.074 us; speedup 1.0000x reference)
//
#include <hip/hip_runtime.h>
#include <math.h>

// QConv2d: new_rho = kron(Ux,Uy) @ rho @ kron(Ux,Uy)^T
// Ux,Uy 32x32 block-diagonal with four IDENTICAL 8x8 orthogonal blocks.
// Four independent length-8 contractions on axes (x1,y1,x2,y2).
//
// Block = (b,bx1,by1,bx2) = 64 rows x 256 contiguous cols, 256 threads.
//  - MONOLITHIC load: all 64 row-loads issued as one batch (one latency
//    exposure), in-place row transform (y1 inner, x1 outer).
//  - Transpose via 32KB [32][256] swizzled LDS, two half-passes.
//  - ALL-WAVES consume: per half, 256 units (rr x by2 x ihalf); each thread
//    y2-transforms its (rr,by2) slice (k-streamed, 2x redundant across
//    ihalf) and x2-contracts 4 of 8 output i-groups. No idle waves.
//  - Direct float4 stores.
// Plain __launch_bounds__(256): the (256,4) hint pinned VGPR=64 and spilled
// acc[] (+30MB scratch traffic). Natural ~110 VGPR keeps 4 waves/SIMD.

__global__ void setup_uf(const float* __restrict__ phi_x,
                         const float* __restrict__ phi_y,
                         float* __restrict__ ws) {
    const int t = threadIdx.x;
    if (t < 2) {
        const float* phi = (t == 0) ? phi_x : phi_y;
        float U[8][8];
#pragma unroll
        for (int i = 0; i < 8; ++i)
#pragma unroll
            for (int j = 0; j < 8; ++j) U[i][j] = (i == j) ? 1.0f : 0.0f;
        int idx = 0;
#pragma unroll
        for (int i = 1; i < 8; ++i) {
#pragma unroll
            for (int j = i; j >= 1; --j) {
                const float c = cosf(phi[idx]);
                const float s = sinf(phi[idx]);
#pragma unroll
                for (int m = 0; m < 8; ++m) {
                    const float a = U[j - 1][m], b = U[j][m];
                    U[j - 1][m] = c * a + s * b;
                    U[j][m]     = -s * a + c * b;
                }
                ++idx;
            }
        }
        float* o = ws + t * 64;
#pragma unroll
        for (int i = 0; i < 8; ++i)
#pragma unroll
            for (int j = 0; j < 8; ++j) o[i * 8 + j] = U[i][j];
    }
}

// contract the INNER index (stride 1 within groups of 8) of a[64] with M[8][8]
#define CONTRACT_INNER(M, a)                                                   \
    _Pragma("unroll")                                                          \
    for (int _g = 0; _g < 8; ++_g) {                                           \
        float _tmp[8];                                                         \
        _Pragma("unroll")                                                      \
        for (int _i = 0; _i < 8; ++_i) {                                       \
            float _acc = 0.0f;                                                 \
            _Pragma("unroll")                                                  \
            for (int _k = 0; _k < 8; ++_k)                                     \
                _acc = fmaf((M)[_i * 8 + _k], (a)[_g * 8 + _k], _acc);         \
            _tmp[_i] = _acc;                                                   \
        }                                                                      \
        _Pragma("unroll")                                                      \
        for (int _i = 0; _i < 8; ++_i) (a)[_g * 8 + _i] = _tmp[_i];            \
    }

// contract the OUTER index (stride 8) of a[64] with M[8][8]
#define CONTRACT_OUTER(M, a)                                                   \
    _Pragma("unroll")                                                          \
    for (int _g = 0; _g < 8; ++_g) {                                           \
        float _tmp[8];                                                         \
        _Pragma("unroll")                                                      \
        for (int _i = 0; _i < 8; ++_i) {                                       \
            float _acc = 0.0f;                                                 \
            _Pragma("unroll")                                                  \
            for (int _k = 0; _k < 8; ++_k)                                     \
                _acc = fmaf((M)[_i * 8 + _k], (a)[_k * 8 + _g], _acc);         \
            _tmp[_i] = _acc;                                                   \
        }                                                                      \
        _Pragma("unroll")                                                      \
        for (int _i = 0; _i < 8; ++_i) (a)[_i * 8 + _g] = _tmp[_i];            \
    }

// All-waves consume of one 32-row half held in S (swizzled [32][256]).
// Unit: (rr5 = t&31, by2 = (t>>5)&3, ihalf = t>>7). k-streamed:
//   per k: 2x ds_read_b128 -> y2-transform (64 FMA) -> x2-accumulate into
//   q[4][8] for i in [ihalf*4, ihalf*4+4)  (32 FMA).
__device__ __forceinline__ void consume_half(const float* __restrict__ S,
                                             const float* __restrict__ UX,
                                             const float* __restrict__ UY,
                                             float* __restrict__ out,
                                             size_t B0, int rowbase, int bx2,
                                             int t, int base) {
    const int rr5   = t & 31;
    const int by2   = (t >> 5) & 3;
    const int ihalf = t >> 7;
    const int r7    = rr5 & 7;
    const float* __restrict__ Srow = S + rr5 * 256;

    float q[32];
#pragma unroll
    for (int k = 0; k < 8; ++k) {
        const int c0 = (((k * 8 + by2 * 2 + 0) ^ r7) << 2);
        const int c1 = (((k * 8 + by2 * 2 + 1) ^ r7) << 2);
        const float4 a = *reinterpret_cast<const float4*>(&Srow[c0]);
        const float4 bq = *reinterpret_cast<const float4*>(&Srow[c1]);
        float raw[8] = {a.x, a.y, a.z, a.w, bq.x, bq.y, bq.z, bq.w};
        float w[8];
#pragma unroll
        for (int jj = 0; jj < 8; ++jj) {
            float acc = 0.0f;
#pragma unroll
            for (int j = 0; j < 8; ++j)
                acc = fmaf(UY[jj * 8 + j], raw[j], acc);
            w[jj] = acc;
        }
#pragma unroll
        for (int ii = 0; ii < 4; ++ii) {
            const float ux = UX[(ihalf * 4 + ii) * 8 + k];
#pragma unroll
            for (int jj = 0; jj < 8; ++jj) {
                if (k == 0) q[ii * 8 + jj] = ux * w[jj];
                else        q[ii * 8 + jj] = fmaf(ux, w[jj], q[ii * 8 + jj]);
            }
        }
    }

    const int rr = base + rr5;
    const int gr = rowbase + ((rr >> 3) * 32) + (rr & 7);
    float* __restrict__ dst =
        out + B0 + (size_t)gr * 1024 + bx2 * 256 + by2 * 8 + ihalf * 128;
#pragma unroll
    for (int ii = 0; ii < 4; ++ii) {
        *reinterpret_cast<float4*>(dst + ii * 32) =
            make_float4(q[ii * 8 + 0], q[ii * 8 + 1], q[ii * 8 + 2], q[ii * 8 + 3]);
        *reinterpret_cast<float4*>(dst + ii * 32 + 4) =
            make_float4(q[ii * 8 + 4], q[ii * 8 + 5], q[ii * 8 + 6], q[ii * 8 + 7]);
    }
}

__global__ __launch_bounds__(256) void qconv_fused(const float* __restrict__ rho,
                                                   const float* __restrict__ ws,
                                                   float* __restrict__ out) {
    __shared__ float S[8192];  // [32 rows][256 cols] swizzled = 32 KB
    const int t   = threadIdx.x;
    const int bid = blockIdx.x;
    const int bx2 = bid & 3;
    const int by1 = (bid >> 2) & 3;
    const int bx1 = (bid >> 4) & 3;
    const int b   = bid >> 6;

    const float* __restrict__ UX = ws;       // Ufx[8][8] (uniform -> s_load)
    const float* __restrict__ UY = ws + 64;  // Ufy[8][8]

    const size_t B0      = (size_t)b << 20;
    const int    rowbase = bx1 * 256 + by1 * 8;
    const int    cg      = bx2 * 256 + t;

    const float* __restrict__ src = rho + B0 + (size_t)rowbase * 1024 + cg;

    // ---- monolithic load: all 64 independent loads in one batch ----
    float v[64];
#pragma unroll
    for (int i = 0; i < 8; ++i)
#pragma unroll
        for (int j = 0; j < 8; ++j)
            v[i * 8 + j] = src[(size_t)(i * 32 + j) * 1024];

    // ---- row transform in place: y1 (inner), x1 (outer) ----
    CONTRACT_INNER(UY, v)
    CONTRACT_OUTER(UX, v)

    // swizzled column slot per row-parity: chunk (t>>2) XOR'd by (r&7)
    int cswz[8];
#pragma unroll
    for (int r7 = 0; r7 < 8; ++r7)
        cswz[r7] = ((((t >> 2) ^ r7) << 2) | (t & 3));

    // ---- half-pass 1: rows 0..31 ----
#pragma unroll
    for (int r = 0; r < 32; ++r) S[r * 256 + cswz[r & 7]] = v[r];
    __syncthreads();
    consume_half(S, UX, UY, out, B0, rowbase, bx2, t, 0);
    __syncthreads();

    // ---- half-pass 2: rows 32..63 ----
#pragma unroll
    for (int r = 32; r < 64; ++r) S[(r - 32) * 256 + cswz[r & 7]] = v[r];
    __syncthreads();
    consume_half(S, UX, UY, out, B0, rowbase, bx2, t, 32);
}

extern "C" void kernel_launch(void* const* d_in, const int* in_sizes, int n_in,
                              void* d_out, int out_size, void* d_ws, size_t ws_size,
                              hipStream_t stream) {
    const float* rho   = (const float*)d_in[0];
    const float* phi_x = (const float*)d_in[1];
    const float* phi_y = (const float*)d_in[2];
    float* out = (float*)d_out;
    float* ws  = (float*)d_ws;

    setup_uf<<<1, 64, 0, stream>>>(phi_x, phi_y, ws);
    qconv_fused<<<1024, 256, 0, stream>>>(rho, ws, out);
}

// Round 8
// 46.990 us; speedup vs baseline: 1.0444x; 1.0444x over previous
//
#include <hip/hip_runtime.h>
#include <hip/hip_bf16.h>
#include <math.h>

// QConv2d: new_rho = kron(Ux,Uy) @ rho @ kron(Ux,Uy)^T
// Ux,Uy 32x32 block-diagonal with four IDENTICAL 8x8 orthogonal blocks.
// Four independent length-8 contractions on axes (x1,y1,x2,y2).
//
// Block = (b,bx1,by1,bx2) = 64 rows x 256 contiguous cols, 256 threads.
//  - thread t owns column bx2*256+t: 64 coalesced dword loads, row transform
//    (y1 inner, x1 outer) in registers (1024 FMA).
//  - stage ENTIRE 64x256 tile to LDS as BF16 (32KB) -> ONE barrier, no
//    half-passes. Swizzle: 16B-slot index slot = (col>>3) ^ ((row<<1)&31)
//    => b16 writes and b128 reads both land 2 lanes/bank (free).
//  - consume: thread (rr=t>>2, by2=t&3): 8x ds_read_b128 (8 bf16 each),
//    y2-transform (512 FMA) + x2-mix (512 FMA), NON-redundant, all threads.
//  - stores: by2 lanes adjacent -> 4 lanes cover 128B contiguous.
// Precision: row transform is orthogonal, staged vals ~N(0,1); bf16 RNE
// adds ~0.01 absmax (threshold 0.107).

__global__ void setup_uf(const float* __restrict__ phi_x,
                         const float* __restrict__ phi_y,
                         float* __restrict__ ws) {
    const int t = threadIdx.x;
    if (t < 2) {
        const float* phi = (t == 0) ? phi_x : phi_y;
        float U[8][8];
#pragma unroll
        for (int i = 0; i < 8; ++i)
#pragma unroll
            for (int j = 0; j < 8; ++j) U[i][j] = (i == j) ? 1.0f : 0.0f;
        int idx = 0;
#pragma unroll
        for (int i = 1; i < 8; ++i) {
#pragma unroll
            for (int j = i; j >= 1; --j) {
                const float c = cosf(phi[idx]);
                const float s = sinf(phi[idx]);
#pragma unroll
                for (int m = 0; m < 8; ++m) {
                    const float a = U[j - 1][m], b = U[j][m];
                    U[j - 1][m] = c * a + s * b;
                    U[j][m]     = -s * a + c * b;
                }
                ++idx;
            }
        }
        float* o = ws + t * 64;
#pragma unroll
        for (int i = 0; i < 8; ++i)
#pragma unroll
            for (int j = 0; j < 8; ++j) o[i * 8 + j] = U[i][j];
    }
}

// contract the INNER index (stride 1 within groups of 8) of a[64] with M[8][8]
#define CONTRACT_INNER(M, a)                                                   \
    _Pragma("unroll")                                                          \
    for (int _g = 0; _g < 8; ++_g) {                                           \
        float _tmp[8];                                                         \
        _Pragma("unroll")                                                      \
        for (int _i = 0; _i < 8; ++_i) {                                       \
            float _acc = 0.0f;                                                 \
            _Pragma("unroll")                                                  \
            for (int _k = 0; _k < 8; ++_k)                                     \
                _acc = fmaf((M)[_i * 8 + _k], (a)[_g * 8 + _k], _acc);         \
            _tmp[_i] = _acc;                                                   \
        }                                                                      \
        _Pragma("unroll")                                                      \
        for (int _i = 0; _i < 8; ++_i) (a)[_g * 8 + _i] = _tmp[_i];            \
    }

// contract the OUTER index (stride 8) of a[64] with M[8][8]
#define CONTRACT_OUTER(M, a)                                                   \
    _Pragma("unroll")                                                          \
    for (int _g = 0; _g < 8; ++_g) {                                           \
        float _tmp[8];                                                         \
        _Pragma("unroll")                                                      \
        for (int _i = 0; _i < 8; ++_i) {                                       \
            float _acc = 0.0f;                                                 \
            _Pragma("unroll")                                                  \
            for (int _k = 0; _k < 8; ++_k)                                     \
                _acc = fmaf((M)[_i * 8 + _k], (a)[_k * 8 + _g], _acc);         \
            _tmp[_i] = _acc;                                                   \
        }                                                                      \
        _Pragma("unroll")                                                      \
        for (int _i = 0; _i < 8; ++_i) (a)[_i * 8 + _g] = _tmp[_i];            \
    }

__global__ __launch_bounds__(256) void qconv_fused(const float* __restrict__ rho,
                                                   const float* __restrict__ ws,
                                                   float* __restrict__ out) {
    // [64 rows][32 slots of 8 bf16], slot-swizzled: 32 KB
    __shared__ __align__(16) unsigned short Sh[16384];
    const int t   = threadIdx.x;
    const int bid = blockIdx.x;
    const int bx2 = bid & 3;
    const int by1 = (bid >> 2) & 3;
    const int bx1 = (bid >> 4) & 3;
    const int b   = bid >> 6;

    const float* __restrict__ UX = ws;       // Ufx[8][8] (uniform -> s_load)
    const float* __restrict__ UY = ws + 64;  // Ufy[8][8]

    const size_t B0      = (size_t)b << 20;
    const int    rowbase = bx1 * 256 + by1 * 8;
    const int    cg      = bx2 * 256 + t;

    const float* __restrict__ src = rho + B0 + (size_t)rowbase * 1024 + cg;

    // ---- monolithic load: 64 independent coalesced dword loads ----
    float v[64];
#pragma unroll
    for (int i = 0; i < 8; ++i)
#pragma unroll
        for (int j = 0; j < 8; ++j)
            v[i * 8 + j] = src[(size_t)(i * 32 + j) * 1024];

    // ---- row transform in place: y1 (inner), x1 (outer) ----
    CONTRACT_INNER(UY, v)
    CONTRACT_OUTER(UX, v)

    // ---- stage whole tile as bf16, swizzled b16 writes (2-way, free) ----
    {
        const int sb = t >> 3;     // thread's natural 16B slot
        const int il = t & 7;      // position within slot
#pragma unroll
        for (int r = 0; r < 64; ++r) {
            const int slot = sb ^ ((r << 1) & 31);
            __hip_bfloat16 h = __float2bfloat16(v[r]);
            Sh[r * 256 + slot * 8 + il] = *reinterpret_cast<unsigned short*>(&h);
        }
    }
    __syncthreads();

    // ---- consume: thread (rr = t>>2, by2 = t&3), non-redundant ----
    const int rr  = t >> 2;
    const int by2 = t & 3;
    const int rsw = (rr << 1) & 31;
    const unsigned short* __restrict__ Srow = Sh + rr * 256;

    float q[64];
#pragma unroll
    for (int x2 = 0; x2 < 8; ++x2) {
        const int slot = (x2 * 4 + by2) ^ rsw;
        const uint4 u = *reinterpret_cast<const uint4*>(Srow + slot * 8);
        float raw[8];
        raw[0] = __uint_as_float(u.x << 16);
        raw[1] = __uint_as_float(u.x & 0xffff0000u);
        raw[2] = __uint_as_float(u.y << 16);
        raw[3] = __uint_as_float(u.y & 0xffff0000u);
        raw[4] = __uint_as_float(u.z << 16);
        raw[5] = __uint_as_float(u.z & 0xffff0000u);
        raw[6] = __uint_as_float(u.w << 16);
        raw[7] = __uint_as_float(u.w & 0xffff0000u);

        float w8[8];
#pragma unroll
        for (int jj = 0; jj < 8; ++jj) {
            float a = 0.0f;
#pragma unroll
            for (int j = 0; j < 8; ++j)
                a = fmaf(UY[jj * 8 + j], raw[j], a);
            w8[jj] = a;
        }
#pragma unroll
        for (int xp = 0; xp < 8; ++xp) {
            const float ux = UX[xp * 8 + x2];
#pragma unroll
            for (int jj = 0; jj < 8; ++jj) {
                if (x2 == 0) q[xp * 8 + jj] = ux * w8[jj];
                else         q[xp * 8 + jj] = fmaf(ux, w8[jj], q[xp * 8 + jj]);
            }
        }
    }

    // ---- stores: by2 lanes adjacent -> 128B-contiguous per 4 lanes ----
    const int gr = rowbase + ((rr >> 3) * 32) + (rr & 7);
    float* __restrict__ dst = out + B0 + (size_t)gr * 1024 + bx2 * 256 + by2 * 8;
#pragma unroll
    for (int xp = 0; xp < 8; ++xp) {
        *reinterpret_cast<float4*>(dst + xp * 32) =
            make_float4(q[xp * 8 + 0], q[xp * 8 + 1], q[xp * 8 + 2], q[xp * 8 + 3]);
        *reinterpret_cast<float4*>(dst + xp * 32 + 4) =
            make_float4(q[xp * 8 + 4], q[xp * 8 + 5], q[xp * 8 + 6], q[xp * 8 + 7]);
    }
}

extern "C" void kernel_launch(void* const* d_in, const int* in_sizes, int n_in,
                              void* d_out, int out_size, void* d_ws, size_t ws_size,
                              hipStream_t stream) {
    const float* rho   = (const float*)d_in[0];
    const float* phi_x = (const float*)d_in[1];
    const float* phi_y = (const float*)d_in[2];
    float* out = (float*)d_out;
    float* ws  = (float*)d_ws;

    setup_uf<<<1, 64, 0, stream>>>(phi_x, phi_y, ws);
    qconv_fused<<<1024, 256, 0, stream>>>(rho, ws, out);
}